// Round 3
// baseline (917.577 us; speedup 1.0000x reference)
//
#include <hip/hip_runtime.h>

// GNNLayer: 3 MLPs (node/message/final). BN folded into GEMM weights.
// bf16 storage, fp32 MFMA accumulation, fp32 stats.
// Workspace-adaptive: peak use = 68 + 128/Cq MiB, Cq in {1,2,4,8} chosen
// from ws_size; d_out doubles as scratch for the bf16 final-MLP input.
// No global_load_lds this round: manual vector-load + ds_write staging.

typedef __attribute__((ext_vector_type(8))) short short8;
typedef __attribute__((ext_vector_type(4))) float f32x4;

__device__ __forceinline__ unsigned short f2bu(float f) {
    unsigned int x = __float_as_uint(f);
    x += 0x7fffu + ((x >> 16) & 1u);
    return (unsigned short)(x >> 16);
}
__device__ __forceinline__ float b2f(unsigned short u) {
    return __uint_as_float(((unsigned int)u) << 16);
}
__device__ __forceinline__ float sigmoidf_(float v) {
    return 1.0f / (1.0f + __expf(-v));
}

__global__ __launch_bounds__(256) void k_zero4(float4* p, int n4) {
    int i = blockIdx.x * 256 + threadIdx.x;
    if (i < n4) p[i] = make_float4(0.f, 0.f, 0.f, 0.f);
}

// per-feature sum/sumsq of x [65536,256] (no store)
__global__ __launch_bounds__(256) void k_colstats(const float* __restrict__ x,
                                                  float* __restrict__ ssum,
                                                  float* __restrict__ ssq) {
    const int c = threadIdx.x;
    const int r0 = blockIdx.x * 64;
    float s = 0.f, q = 0.f;
    for (int r = r0; r < r0 + 64; ++r) {
        float v = x[(size_t)r * 256 + c];
        s += v; q += v * v;
    }
    atomicAdd(&ssum[c], s);
    atomicAdd(&ssq[c], q);
}

// fold BN into weights: Bt[j][k] = s_k*W[k][j] (bf16, [N][K]);
// bias[j] (+)= c[j] + sum_k t_k*W[k][j]. One block per output column j.
__global__ __launch_bounds__(256) void k_fold(const float* __restrict__ W,      // [Kc][N]
                                              const float* __restrict__ gamma,
                                              const float* __restrict__ beta,
                                              const float* __restrict__ ssum,
                                              const float* __restrict__ ssq,
                                              const float* __restrict__ cvec,   // [N] or null
                                              float inv_count, int N, int Kc,
                                              unsigned short* __restrict__ Bt,  // [N][Kc]
                                              float* __restrict__ bias, int bias_add) {
    const int j = blockIdx.x;
    const int t = threadIdx.x;
    float part = 0.f;
    for (int k = t; k < Kc; k += 256) {
        float mu  = ssum[k] * inv_count;
        float var = ssq[k] * inv_count - mu * mu;
        float s   = gamma[k] * rsqrtf(var + 1e-5f);
        float tt  = beta[k] - mu * s;
        float w   = W[(size_t)k * N + j];
        Bt[(size_t)j * Kc + k] = f2bu(s * w);
        part += tt * w;
    }
    __shared__ float red[256];
    red[t] = part;
    __syncthreads();
    for (int s2 = 128; s2 > 0; s2 >>= 1) {
        if (t < s2) red[t] += red[t + s2];
        __syncthreads();
    }
    if (t == 0) {
        if (bias_add) atomicAdd(&bias[j], red[0]);
        else bias[j] = red[0] + cvec[j];
    }
}

// stats of h_m = relu(P+Q) over one chunk of PQ [G,1024] (chunk-local rows)
__global__ __launch_bounds__(512) void k_msgstats(const unsigned short* __restrict__ PQ,
                                                  float* __restrict__ ssum,
                                                  float* __restrict__ ssq) {
    const int f = threadIdx.x;
    float s = 0.f, q = 0.f;
    const int r0 = blockIdx.x * 48;
    for (int r = r0; r < r0 + 48; ++r) {
        int b  = r / 12;
        int p  = r - b * 12;
        int si = p / 3;
        int t  = p - si * 3;
        int di = t + (t >= si ? 1 : 0);
        float pv = b2f(PQ[(size_t)(b * 4 + si) * 1024 + f]);
        float qv = b2f(PQ[(size_t)(b * 4 + di) * 1024 + 512 + f]);
        float v = fmaxf(pv + qv, 0.f);
        s += v; q += v * v;
    }
    atomicAdd(&ssum[f], s);
    atomicAdd(&ssq[f], q);
}

// finish fp32 agg -> in_f[:,256:512] bf16 + stats
__global__ __launch_bounds__(256) void k_aggfin(const float* __restrict__ agg,  // [65536,256]
                                                unsigned short* __restrict__ inf_,
                                                float* __restrict__ ssum,
                                                float* __restrict__ ssq) {
    const int f = threadIdx.x;
    const int g0 = blockIdx.x * 64;
    float s = 0.f, q = 0.f;
    for (int g = g0; g < g0 + 64; ++g) {
        float v = agg[(size_t)g * 256 + f];
        inf_[(size_t)g * 512 + 256 + f] = f2bu(v);
        s += v; q += v * v;
    }
    atomicAdd(&ssum[f], s);
    atomicAdd(&ssq[f], q);
}

// 128x128-tile bf16 MFMA GEMM, Bt is [N][K]. Manual staging (no global_load_lds).
// AF32: A operand is fp32 (converted to bf16 during staging).
// EPI: 1 bias+relu+stats bf16; 2 bias+sigmoid+stats bf16; 4 bias+sigmoid f32; 5 bias bf16
template <int EPI, int AF32>
__global__ __launch_bounds__(256) void k_gemm(const void* __restrict__ Av, int lda,
                                              const unsigned short* __restrict__ Bt,
                                              void* __restrict__ C, int ldc,
                                              const float* __restrict__ bias,
                                              float* __restrict__ ssum, float* __restrict__ ssq,
                                              int K) {
    const int n0 = blockIdx.x * 128;
    const int m0 = blockIdx.y * 128;
    const int tid = threadIdx.x;
    const int w = tid >> 6;
    const int lane = tid & 63;
    const int q = lane >> 4;
    const int l = lane & 15;
    const int wm = w >> 1;
    const int wn = w & 1;

    __shared__ __align__(16) unsigned short lA[128 * 32];  // [m][k]
    __shared__ __align__(16) unsigned short lB[128 * 32];  // [n][k]
    __shared__ float s_sum[128];
    __shared__ float s_sq[128];

    if ((EPI == 1 || EPI == 2) && tid < 128) { s_sum[tid] = 0.f; s_sq[tid] = 0.f; }

    f32x4 acc[4][4] = {};

    const int rsub = tid >> 2;          // 0..63
    const int ksub = (tid & 3) * 8;     // 0,8,16,24
    const unsigned short* gA16 = (const unsigned short*)Av + (size_t)(m0 + rsub) * lda + ksub;
    const float*          gA32 = (const float*)Av + (size_t)(m0 + rsub) * lda + ksub;
    const unsigned short* gB = Bt + (size_t)(n0 + rsub) * K + ksub;
    unsigned short* wA = lA + rsub * 32 + ksub;
    unsigned short* wB = lB + rsub * 32 + ksub;

    for (int k0 = 0; k0 < K; k0 += 32) {
        short8 a8[2], b8[2];
#pragma unroll
        for (int t = 0; t < 2; ++t) {
            if (AF32) {
                float4 f0 = *(const float4*)(gA32 + (size_t)t * 64 * lda + k0);
                float4 f1 = *(const float4*)(gA32 + (size_t)t * 64 * lda + k0 + 4);
                short8 o;
                o[0] = (short)f2bu(f0.x); o[1] = (short)f2bu(f0.y);
                o[2] = (short)f2bu(f0.z); o[3] = (short)f2bu(f0.w);
                o[4] = (short)f2bu(f1.x); o[5] = (short)f2bu(f1.y);
                o[6] = (short)f2bu(f1.z); o[7] = (short)f2bu(f1.w);
                a8[t] = o;
            } else {
                a8[t] = *(const short8*)(gA16 + (size_t)t * 64 * lda + k0);
            }
            b8[t] = *(const short8*)(gB + (size_t)t * 64 * K + k0);
        }
        __syncthreads();  // previous iteration's LDS reads complete
#pragma unroll
        for (int t = 0; t < 2; ++t) {
            *(short8*)(wA + t * 64 * 32) = a8[t];
            *(short8*)(wB + t * 64 * 32) = b8[t];
        }
        __syncthreads();
        short8 av[4], bv[4];
#pragma unroll
        for (int i = 0; i < 4; ++i)
            av[i] = *(const short8*)(lA + ((wm * 64 + i * 16 + l) * 32 + q * 8));
#pragma unroll
        for (int j = 0; j < 4; ++j)
            bv[j] = *(const short8*)(lB + ((wn * 64 + j * 16 + l) * 32 + q * 8));
#pragma unroll
        for (int i = 0; i < 4; ++i)
#pragma unroll
            for (int j = 0; j < 4; ++j)
                acc[i][j] = __builtin_amdgcn_mfma_f32_16x16x32_bf16(av[i], bv[j], acc[i][j], 0, 0, 0);
    }

#pragma unroll
    for (int j = 0; j < 4; ++j) {
        const int colL = wn * 64 + j * 16 + l;
        const int col = n0 + colL;
        const float bb = bias[col];
        float psum = 0.f, psq = 0.f;
#pragma unroll
        for (int i = 0; i < 4; ++i) {
            const int rowL = wm * 64 + i * 16 + q * 4;
#pragma unroll
            for (int r = 0; r < 4; ++r) {
                float v = acc[i][j][r] + bb;
                if (EPI == 1) v = fmaxf(v, 0.f);
                if (EPI == 2 || EPI == 4) v = sigmoidf_(v);
                const size_t off = (size_t)(m0 + rowL + r) * ldc + col;
                if (EPI == 4) ((float*)C)[off] = v;
                else ((unsigned short*)C)[off] = f2bu(v);
                psum += v; psq += v * v;
            }
        }
        if (EPI == 1 || EPI == 2) {
            atomicAdd(&s_sum[colL], psum);
            atomicAdd(&s_sq[colL], psq);
        }
    }
    if (EPI == 1 || EPI == 2) {
        __syncthreads();
        if (tid < 128) {
            atomicAdd(&ssum[n0 + tid], s_sum[tid]);
            atomicAdd(&ssq[n0 + tid], s_sq[tid]);
        }
    }
}

// x_msg GEMM over one chunk: A-tile = relu(P[b,si]+Q[b,di]) built on the fly
// (chunk-local rows). Output: atomicAdd sigmoid(...)/3 into agg (pre-offset).
__global__ __launch_bounds__(256) void k_gemm_msg(const unsigned short* __restrict__ PQ, // [G,1024] local
                                                  const unsigned short* __restrict__ Bt, // [256][512]
                                                  float* __restrict__ agg,               // pre-offset
                                                  const float* __restrict__ bias) {
    const int K = 512;
    const int n0 = blockIdx.x * 128;
    const int m0 = blockIdx.y * 128;  // chunk-local msg row
    const int tid = threadIdx.x;
    const int w = tid >> 6;
    const int lane = tid & 63;
    const int q = lane >> 4;
    const int l = lane & 15;
    const int wm = w >> 1;
    const int wn = w & 1;

    __shared__ __align__(16) unsigned short lA[128 * 32];
    __shared__ __align__(16) unsigned short lB[128 * 32];

    f32x4 acc[4][4] = {};

    const int rsub = tid >> 2;
    const int ksub = (tid & 3) * 8;
    size_t aP[2], aQ[2];
#pragma unroll
    for (int t = 0; t < 2; ++t) {
        int r = m0 + t * 64 + rsub;
        int b = r / 12;
        int p = r - b * 12;
        int si = p / 3;
        int tt = p - si * 3;
        int di = tt + (tt >= si ? 1 : 0);
        aP[t] = (size_t)(b * 4 + si) * 1024 + ksub;
        aQ[t] = (size_t)(b * 4 + di) * 1024 + 512 + ksub;
    }
    const unsigned short* gB = Bt + (size_t)(n0 + rsub) * K + ksub;
    unsigned short* wA = lA + rsub * 32 + ksub;
    unsigned short* wB = lB + rsub * 32 + ksub;

    for (int k0 = 0; k0 < K; k0 += 32) {
        short8 a8[2], b8[2];
#pragma unroll
        for (int t = 0; t < 2; ++t) {
            short8 p8 = *(const short8*)(PQ + aP[t] + k0);
            short8 q8 = *(const short8*)(PQ + aQ[t] + k0);
            short8 o;
#pragma unroll
            for (int e = 0; e < 8; ++e) {
                float v = b2f((unsigned short)p8[e]) + b2f((unsigned short)q8[e]);
                o[e] = (short)f2bu(fmaxf(v, 0.f));
            }
            a8[t] = o;
            b8[t] = *(const short8*)(gB + (size_t)t * 64 * K + k0);
        }
        __syncthreads();
#pragma unroll
        for (int t = 0; t < 2; ++t) {
            *(short8*)(wA + t * 64 * 32) = a8[t];
            *(short8*)(wB + t * 64 * 32) = b8[t];
        }
        __syncthreads();
        short8 av[4], bv[4];
#pragma unroll
        for (int i = 0; i < 4; ++i)
            av[i] = *(const short8*)(lA + ((wm * 64 + i * 16 + l) * 32 + q * 8));
#pragma unroll
        for (int j = 0; j < 4; ++j)
            bv[j] = *(const short8*)(lB + ((wn * 64 + j * 16 + l) * 32 + q * 8));
#pragma unroll
        for (int i = 0; i < 4; ++i)
#pragma unroll
            for (int j = 0; j < 4; ++j)
                acc[i][j] = __builtin_amdgcn_mfma_f32_16x16x32_bf16(av[i], bv[j], acc[i][j], 0, 0, 0);
    }

#pragma unroll
    for (int j = 0; j < 4; ++j) {
        const int col = n0 + wn * 64 + j * 16 + l;
        const float bb = bias[col];
#pragma unroll
        for (int i = 0; i < 4; ++i) {
            const int rowL = wm * 64 + i * 16 + q * 4;
#pragma unroll
            for (int r = 0; r < 4; ++r) {
                float v = sigmoidf_(acc[i][j][r] + bb);
                const int row = m0 + rowL + r;  // local msg row; /3 -> local node row
                atomicAdd(&agg[(size_t)(row / 3) * 256 + col], v * (1.f / 3.f));
            }
        }
    }
}

extern "C" void kernel_launch(void* const* d_in, const int* in_sizes, int n_in,
                              void* d_out, int out_size, void* d_ws, size_t ws_size,
                              hipStream_t stream) {
    const float* x   = (const float*)d_in[0];
    const float* ng0 = (const float*)d_in[1];
    const float* nb0 = (const float*)d_in[2];
    const float* nW0 = (const float*)d_in[3];
    const float* nc0 = (const float*)d_in[4];
    const float* ng1 = (const float*)d_in[5];
    const float* nb1 = (const float*)d_in[6];
    const float* nW1 = (const float*)d_in[7];
    const float* nc1 = (const float*)d_in[8];
    const float* mg0 = (const float*)d_in[9];
    const float* mb0 = (const float*)d_in[10];
    const float* mW0 = (const float*)d_in[11];
    const float* mc0 = (const float*)d_in[12];
    const float* mg1 = (const float*)d_in[13];
    const float* mb1 = (const float*)d_in[14];
    const float* mW1 = (const float*)d_in[15];
    const float* mc1 = (const float*)d_in[16];
    const float* fg0 = (const float*)d_in[17];
    const float* fb0 = (const float*)d_in[18];
    const float* fW0 = (const float*)d_in[19];
    const float* fc0 = (const float*)d_in[20];
    const float* fg1 = (const float*)d_in[21];
    const float* fb1 = (const float*)d_in[22];
    const float* fW1 = (const float*)d_in[23];
    const float* fc1 = (const float*)d_in[24];

    char* ws = (char*)d_ws;
    const size_t MiB = 1024 * 1024;

    // chunk count for PQ: peak ws = 68 + 128/Cq MiB
    int Cq = 1;
    while (Cq < 8 && (68 + 128 / Cq) * MiB > ws_size) Cq *= 2;
    const int G = 65536 / Cq;  // node rows per chunk (multiple of 4: graphs don't straddle)

    // header [0,4MiB): stats (zeroed) + biases + folded weights
    float* stat = (float*)ws;
    float* sx_s   = stat + 0;     // 256
    float* sx_q   = stat + 256;   // 256
    float* shn_s  = stat + 512;   // 512
    float* shn_q  = stat + 1024;
    float* shm_s  = stat + 1536;
    float* shm_q  = stat + 2048;
    float* sif_s  = stat + 2560;
    float* sif_q  = stat + 3072;
    float* shf_s  = stat + 3584;
    float* shf_q  = stat + 4096;  // -> 4608
    float* biasPQ = stat + 4608;  // 1024, upper 512 stay zero
    // zeroed region ends at 5632 floats
    float* bias_n = stat + 5632;  // 512
    float* b1n    = stat + 6144;  // 256
    float* b1m    = stat + 6400;  // 256
    float* b0f    = stat + 6656;  // 512
    float* b1f    = stat + 7168;  // 256

    unsigned short* An  = (unsigned short*)(ws + 256 * 1024);  // [512][256]
    unsigned short* Btm = An + 512 * 256;                      // [1024][256]
    unsigned short* A1n = Btm + 1024 * 256;                    // [256][512]
    unsigned short* A1m = A1n + 256 * 512;                     // [256][512]
    unsigned short* A0f = A1m + 256 * 512;                     // [512][512]
    unsigned short* A1f = A0f + 512 * 512;                     // [256][512]

    // [4,68): hn (bf16, live gemm1a..gemm2n) -> agg (fp32, live zero..aggfin)
    //         -> hf (bf16, live gemm3..gemm4)
    // [68, 68+128/Cq): PQ chunk buffer
    unsigned short* hn    = (unsigned short*)(ws + 4 * MiB);
    float*          agg   = (float*)(ws + 4 * MiB);
    unsigned short* hf    = (unsigned short*)(ws + 4 * MiB);
    unsigned short* PQbuf = (unsigned short*)(ws + 68 * MiB);
    unsigned short* inf   = (unsigned short*)d_out;  // [65536,512] bf16, dead before gemm4

    const float inv1 = 1.f / 65536.f;
    const float invM = 1.f / 196608.f;

    // zero stats + biasPQ (5632 floats = 1408 float4)
    k_zero4<<<6, 256, 0, stream>>>((float4*)stat, 1408);

    // x column stats
    k_colstats<<<1024, 256, 0, stream>>>(x, sx_s, sx_q);

    // fold BN0 (msg BN0 stats == node BN0 stats: each node appears exactly
    // 3x as src and 3x as dst across the 12 ordered pairs)
    k_fold<<<512, 256, 0, stream>>>(nW0, ng0, nb0, sx_s, sx_q, nc0, inv1, 512, 256, An, bias_n, 0);
    k_fold<<<512, 256, 0, stream>>>(mW0, mg0, mb0, sx_s, sx_q, mc0, inv1, 512, 256, Btm, biasPQ, 0);
    k_fold<<<512, 256, 0, stream>>>(mW0 + 256 * 512, mg0 + 256, mb0 + 256, sx_s, sx_q, nullptr,
                                    inv1, 512, 256, Btm + 512 * 256, biasPQ, 1);

    // h_n = relu(x @ An + bias_n), BN1_n stats  (A is fp32 x, staged-converted)
    k_gemm<1, 1><<<dim3(4, 512), 256, 0, stream>>>(x, 256, An, hn, 512, bias_n, shn_s, shn_q, 256);

    // PQ chunks: PQ = x_chunk @ [Amt|Amb] + [bias_m|0]; accumulate BN1_m stats
    for (int c = 0; c < Cq; ++c) {
        k_gemm<5, 1><<<dim3(8, 512 / Cq), 256, 0, stream>>>(
            x + (size_t)c * G * 256, 256, Btm, PQbuf, 1024, biasPQ, nullptr, nullptr, 256);
        k_msgstats<<<4096 / Cq, 512, 0, stream>>>(PQbuf, shm_s, shm_q);
    }

    // fold BN1
    k_fold<<<256, 256, 0, stream>>>(nW1, ng1, nb1, shn_s, shn_q, nc1, inv1, 256, 512, A1n, b1n, 0);
    k_fold<<<256, 256, 0, stream>>>(mW1, mg1, mb1, shm_s, shm_q, mc1, invM, 256, 512, A1m, b1m, 0);

    // x_node = sigmoid(hn @ A1n + b1n) -> in_f[:,0:256] (in d_out), f-BN0 stats
    k_gemm<2, 0><<<dim3(2, 512), 256, 0, stream>>>(hn, 512, A1n, inf, 512, b1n, sif_s, sif_q, 512);

    // x_agg: zero agg (reuses hn region, hn now dead), then fused msg GEMM chunks
    k_zero4<<<16384, 256, 0, stream>>>((float4*)agg, 4194304);
    for (int c = 0; c < Cq; ++c) {
        if (Cq > 1)  // recompute PQ chunk (Cq==1 kept the full PQ)
            k_gemm<5, 1><<<dim3(8, 512 / Cq), 256, 0, stream>>>(
                x + (size_t)c * G * 256, 256, Btm, PQbuf, 1024, biasPQ, nullptr, nullptr, 256);
        k_gemm_msg<<<dim3(2, 1536 / Cq), 256, 0, stream>>>(PQbuf, A1m, agg + (size_t)c * G * 256, b1m);
    }
    k_aggfin<<<1024, 256, 0, stream>>>(agg, inf, sif_s + 256, sif_q + 256);

    // final MLP
    k_fold<<<512, 256, 0, stream>>>(fW0, fg0, fb0, sif_s, sif_q, fc0, inv1, 512, 512, A0f, b0f, 0);
    k_gemm<1, 0><<<dim3(4, 512), 256, 0, stream>>>(inf, 512, A0f, hf, 512, b0f, shf_s, shf_q, 512);
    k_fold<<<256, 256, 0, stream>>>(fW1, fg1, fb1, shf_s, shf_q, fc1, inv1, 256, 512, A1f, b1f, 0);
    k_gemm<4, 0><<<dim3(2, 512), 256, 0, stream>>>(hf, 512, A1f, d_out, 256, b1f, nullptr, nullptr, 512);

    (void)in_sizes; (void)n_in; (void)out_size;
}